// Round 9
// baseline (95.156 us; speedup 1.0000x reference)
//
#include <hip/hip_runtime.h>
#include <stdint.h>

// ============================================================================
// MEASUREMENT ROUND: kernel code is identical to R8 (best, 85.54 us).
// The launch sequence duplicates gather1 and gather2 (idempotent, bit-exact)
// so dur_us - 85.5 = marginal cost of (g1 + g2 + 2 graph boundaries).
// ============================================================================

#define K_ELL 32      // ELL planes per near/far array (column-major; untouched planes = 0 traffic)
#define K_OVF 16      // overflow planes (out-of-band fallback, expected ~empty)
#define TBS   1024    // build block size
#define RNG_LOG 11
#define RNG   2048    // build block a-range
#define BAND  2048    // in-band limit on (b - v0 - 1); == RNG so each vertex has unique far owner
#define RW    (RNG + BAND)   // 4096 ints = 16 KB LDS
#define BS    256
#define UA    6       // unrolled a-side slots
#define UN    6       // unrolled near-ELL slots
#define UF    4       // unrolled far-ELL slots
#define NXCD  8

// bijective XCD-aware swizzle (m204): blocks with the same hw id % 8 (same XCD)
// get a CONTIGUOUS range of logical block ids -> each XCD owns one vertex band.
__device__ __forceinline__ int xcd_swz(int bid, int nwg) {
    int q = nwg >> 3, r = nwg & 7;
    int x = bid & 7, idx = bid >> 3;
    return (x < r ? x * (q + 1) : r * (q + 1) + (x - r) * q) + idx;
}

// prep (light): offs_a[u] = first edge index with edges[.].x >= u (edges[:,0]
// sorted asc, a<b); zero the counters build's LDS dumps don't cover.
__global__ void prep_kernel(const int2* __restrict__ edges, int* __restrict__ offs_a,
                            int* __restrict__ cntN, int* __restrict__ cntF,
                            int* __restrict__ deg_ovf, int E, int V) {
    int i = blockIdx.x * blockDim.x + threadIdx.x;
    if (i <= E) {
        if (i < E) {
            int lo = (i == 0) ? 0 : edges[i - 1].x + 1;
            int hi = edges[i].x;
            for (int a = lo; a <= hi; a++) offs_a[a] = i;
        } else {
            for (int a = edges[E - 1].x + 1; a <= V; a++) offs_a[a] = E;
        }
    }
    if (i < V) deg_ovf[i] = 0;
    if (i <= RNG) cntF[i] = 0;   // vertices with no far-owner block
    if (i == 0) cntN[0] = 0;     // vertex 0 has no near-owner block
}

// build: heavy blocks (< NBb) do the b-side transpose via LDS-rank atomics into
// column-major near/far ELL; copy blocks (>= NBb) do faces->float (vectorized)
// and v->float4 repack on the ~165 CUs the heavy blocks leave idle.
__global__ __launch_bounds__(TBS) void build_kernel(
        const int2* __restrict__ edges, const int* __restrict__ offs_a,
        int* __restrict__ cntN, int* __restrict__ cntF, int* __restrict__ deg_ovf,
        int* __restrict__ adjN, int* __restrict__ adjF, int* __restrict__ adj_ovf,
        const int* __restrict__ faces, float* __restrict__ out_f,
        const float* __restrict__ v, float4* __restrict__ v4,
        int E, int V, int F3, int NBb) {
    if ((int)blockIdx.x >= NBb) {
        int t = (blockIdx.x - NBb) * TBS + threadIdx.x;
        int T = (gridDim.x - NBb) * TBS;
        if ((((uintptr_t)out_f | (uintptr_t)faces) & 15) == 0) {
            int n4 = F3 >> 2;
            const int4* f4 = (const int4*)faces;
            float4* o4 = (float4*)out_f;
            for (int j = t; j < n4; j += T) {
                int4 a = f4[j];
                o4[j] = make_float4((float)a.x, (float)a.y, (float)a.z, (float)a.w);
            }
            for (int j = (n4 << 2) + t; j < F3; j += T) out_f[j] = (float)faces[j];
        } else {
            for (int j = t; j < F3; j += T) out_f[j] = (float)faces[j];
        }
        if (((uintptr_t)v & 15) == 0) {
            const float4* vv = (const float4*)v;
            int n4v = V >> 2;
            for (int q = t; q < n4v; q += T) {   // 3x float4 in -> 4x float4 out
                float4 a = vv[3 * q], b = vv[3 * q + 1], c = vv[3 * q + 2];
                v4[4 * q + 0] = make_float4(a.x, a.y, a.z, 0.f);
                v4[4 * q + 1] = make_float4(a.w, b.x, b.y, 0.f);
                v4[4 * q + 2] = make_float4(b.z, b.w, c.x, 0.f);
                v4[4 * q + 3] = make_float4(c.y, c.z, c.w, 0.f);
            }
            for (int u = (n4v << 2) + t; u < V; u += T)
                v4[u] = make_float4(v[3 * u], v[3 * u + 1], v[3 * u + 2], 0.f);
        } else {
            for (int u = t; u < V; u += T)
                v4[u] = make_float4(v[3 * u], v[3 * u + 1], v[3 * u + 2], 0.f);
        }
        return;
    }
    __shared__ int cnt[RW];
    const int v0   = blockIdx.x << RNG_LOG;
    const int vEnd = min(v0 + RNG, V);
    for (int i = threadIdx.x; i < RW; i += TBS) cnt[i] = 0;
    const int eBeg = offs_a[v0];
    const int eEnd = offs_a[vEnd];
    __syncthreads();
    for (int i = eBeg + threadIdx.x; i < eEnd; i += TBS) {
        int2 e = edges[i];
        int rel = e.y - (v0 + 1);            // b > a >= v0 -> rel >= 0
        if (rel < RW) {
            int r = atomicAdd(&cnt[rel], 1); // LDS rank = final ELL slot
            if (rel < RNG) { if (r < K_ELL) adjN[(size_t)r * V + e.y] = e.x; }
            else           { if (r < K_ELL) adjF[(size_t)r * V + e.y] = e.x; }
        } else {                              // out-of-band fallback (rare; always correct)
            int r = atomicAdd(&deg_ovf[e.y], 1);
            if (r < K_OVF) adj_ovf[(size_t)r * V + e.y] = e.x;
        }
    }
    __syncthreads();
    for (int i = threadIdx.x; i < RW; i += TBS) {
        int u = v0 + 1 + i;
        if (u < V) {
            if (i < RNG) cntN[u] = cnt[i];   // unique near owner
            else         cntF[u] = cnt[i];   // unique far owner (BAND == RNG)
        }
    }
}

// gather: lambd==1 -> y = nbr_sum/deg (deg==0 -> 0, matches ref).
// XCD-swizzled; 3 latency levels; masked slots clamp to broadcast index 0.
// Pure function of its inputs (no atomics) -> duplicate dispatch is bit-exact.
template <bool PAD>
__global__ void gather_kernel(const float4* __restrict__ x4, const int2* __restrict__ edges,
                              const int* __restrict__ offs_a,
                              const int* __restrict__ cntN, const int* __restrict__ cntF,
                              const int* __restrict__ deg_ovf,
                              const int* __restrict__ adjN, const int* __restrict__ adjF,
                              const int* __restrict__ adj_ovf,
                              float* __restrict__ y, int V, int E) {
    int u = xcd_swz((int)blockIdx.x, (int)gridDim.x) * BS + (int)threadIdx.x;
    if (u >= V) return;
    int aBeg = offs_a[u], aEnd = offs_a[u + 1];
    int cN = cntN[u], cF = cntF[u], dO = deg_ovf[u];
    int da = aEnd - aBeg;
    int kN = cN > K_ELL ? K_ELL : cN;
    int kF = cF > K_ELL ? K_ELL : cF;
    // ---- level 2: all neighbor-index loads issue together ----
    int gA[UA], gN[UN], gF[UF];
    #pragma unroll
    for (int j = 0; j < UA; ++j) gA[j] = edges[min(aBeg + j, E - 1)].y;  // in-bounds
    #pragma unroll
    for (int k = 0; k < UN; ++k) gN[k] = adjN[(size_t)k * V + u];        // coalesced plane reads
    #pragma unroll
    for (int k = 0; k < UF; ++k) gF[k] = adjF[(size_t)k * V + u];
    // ---- level 3: value loads, mask-multiplied ----
    float s0 = 0.f, s1 = 0.f, s2 = 0.f;
    #pragma unroll
    for (int j = 0; j < UA; ++j) {
        float m = (j < da) ? 1.f : 0.f;
        float4 p = x4[(j < da) ? gA[j] : 0];           // masked -> broadcast line
        s0 += m * p.x; s1 += m * p.y; s2 += m * p.z;
    }
    for (int j = UA; j < da; ++j) {                    // rare high-valence tail
        float4 p = x4[edges[aBeg + j].y];
        s0 += p.x; s1 += p.y; s2 += p.z;
    }
    #pragma unroll
    for (int k = 0; k < UN; ++k) {
        float m = (k < kN) ? 1.f : 0.f;
        float4 p = x4[(k < kN) ? gN[k] : 0];
        s0 += m * p.x; s1 += m * p.y; s2 += m * p.z;
    }
    for (int k = UN; k < kN; ++k) {
        float4 p = x4[adjN[(size_t)k * V + u]];
        s0 += p.x; s1 += p.y; s2 += p.z;
    }
    #pragma unroll
    for (int k = 0; k < UF; ++k) {
        float m = (k < kF) ? 1.f : 0.f;
        float4 p = x4[(k < kF) ? gF[k] : 0];
        s0 += m * p.x; s1 += m * p.y; s2 += m * p.z;
    }
    for (int k = UF; k < kF; ++k) {
        float4 p = x4[adjF[(size_t)k * V + u]];
        s0 += p.x; s1 += p.y; s2 += p.z;
    }
    int kO = dO > K_OVF ? K_OVF : dO;
    for (int k = 0; k < kO; ++k) {                     // expected empty
        float4 p = x4[adj_ovf[(size_t)k * V + u]];
        s0 += p.x; s1 += p.y; s2 += p.z;
    }
    int d = da + cN + cF + dO;
    float inv = 1.0f / fmaxf((float)d, 1.0f);
    if (PAD) {
        ((float4*)y)[u] = make_float4(s0 * inv, s1 * inv, s2 * inv, 0.f);
    } else {
        y[3 * u + 0] = s0 * inv;
        y[3 * u + 1] = s1 * inv;
        y[3 * u + 2] = s2 * inv;
    }
}

extern "C" void kernel_launch(void* const* d_in, const int* in_sizes, int n_in,
                              void* d_out, int out_size, void* d_ws, size_t ws_size,
                              hipStream_t stream) {
    const float* v     = (const float*)d_in[0];  // [V,3]
    const int2*  edges = (const int2*)d_in[1];   // [E,2], rows lex-sorted, a<b
    const int*   faces = (const int*)d_in[2];    // [F,3]

    const int V3 = in_sizes[0];
    const int V  = V3 / 3;
    const int E  = in_sizes[1] / 2;
    const int F3 = in_sizes[2];

    float* out_v = (float*)d_out;
    float* out_f = (float*)d_out + V3;

    // ws layout (16B-aligned float4 arrays first): v4[V] | x1[V] | adjN[K_ELL*V] |
    //   adjF[K_ELL*V] | adj_ovf[K_OVF*V] | offs_a[V+1] | cntN[V+1] | cntF[V+1] | deg_ovf[V]
    float4* v4      = (float4*)d_ws;
    float4* x1      = v4 + V;
    int*    adjN    = (int*)(x1 + V);
    int*    adjF    = adjN + (size_t)K_ELL * V;
    int*    adj_ovf = adjF + (size_t)K_ELL * V;
    int*    offs_a  = adj_ovf + (size_t)K_OVF * V;
    int*    cntN    = offs_a + (V + 1);
    int*    cntF    = cntN + (V + 1);
    int*    deg_ovf = cntF + (V + 1);

    const int NBb = (V + RNG - 1) / RNG;          // heavy build blocks (~91)
    const int copyElems = F3 > V ? F3 : V;
    const int NBc = (copyElems + TBS - 1) / TBS;  // copy blocks (~1086)
    const int gP  = (E + 1 + BS - 1) / BS;        // prep covers edges (+V zeroing folded)
    const int gV  = (V + BS - 1) / BS;

    prep_kernel<<<gP, BS, 0, stream>>>(edges, offs_a, cntN, cntF, deg_ovf, E, V);

    build_kernel<<<NBb + NBc, TBS, 0, stream>>>(edges, offs_a, cntN, cntF, deg_ovf,
                                                adjN, adjF, adj_ovf, faces, out_f,
                                                v, v4, E, V, F3, NBb);

    // MEASUREMENT: each gather enqueued TWICE (pure kernel -> bit-exact).
    // dur_us delta vs R8 (85.54) = g1 + g2 + 2 graph boundaries.
    gather_kernel<true ><<<gV, BS, 0, stream>>>(v4, edges, offs_a, cntN, cntF, deg_ovf,
                                                adjN, adjF, adj_ovf, (float*)x1, V, E);
    gather_kernel<true ><<<gV, BS, 0, stream>>>(v4, edges, offs_a, cntN, cntF, deg_ovf,
                                                adjN, adjF, adj_ovf, (float*)x1, V, E);
    gather_kernel<false><<<gV, BS, 0, stream>>>(x1, edges, offs_a, cntN, cntF, deg_ovf,
                                                adjN, adjF, adj_ovf, out_v, V, E);
    gather_kernel<false><<<gV, BS, 0, stream>>>(x1, edges, offs_a, cntN, cntF, deg_ovf,
                                                adjN, adjF, adj_ovf, out_v, V, E);
}

// Round 10
// 92.874 us; speedup vs baseline: 1.0246x; 1.0246x over previous
//
#include <hip/hip_runtime.h>
#include <stdint.h>

// ============================================================================
// MEASUREMENT ROUND 2: kernel code identical to R8 (best, 85.54 us) except
// build_kernel gains a doOvf flag. The launch sequence enqueues build TWICE
// (second with doOvf=0 -> skips deg_ovf/adj_ovf atomics, so the duplicate is
// semantically idempotent). dur_us - 85.54 = build + 1 graph boundary.
// Combined with R9 (g1+g2+2B = 9.62), this fully decomposes the chain.
// ============================================================================

#define K_ELL 32      // ELL planes per near/far array (column-major; untouched planes = 0 traffic)
#define K_OVF 16      // overflow planes (out-of-band fallback, expected ~empty)
#define TBS   1024    // build block size
#define RNG_LOG 11
#define RNG   2048    // build block a-range
#define BAND  2048    // in-band limit on (b - v0 - 1); == RNG so each vertex has unique far owner
#define RW    (RNG + BAND)   // 4096 ints = 16 KB LDS
#define BS    256
#define UA    6       // unrolled a-side slots
#define UN    6       // unrolled near-ELL slots
#define UF    4       // unrolled far-ELL slots
#define NXCD  8

// bijective XCD-aware swizzle (m204): blocks with the same hw id % 8 (same XCD)
// get a CONTIGUOUS range of logical block ids -> each XCD owns one vertex band.
__device__ __forceinline__ int xcd_swz(int bid, int nwg) {
    int q = nwg >> 3, r = nwg & 7;
    int x = bid & 7, idx = bid >> 3;
    return (x < r ? x * (q + 1) : r * (q + 1) + (x - r) * q) + idx;
}

// prep (light): offs_a[u] = first edge index with edges[.].x >= u (edges[:,0]
// sorted asc, a<b); zero the counters build's LDS dumps don't cover.
__global__ void prep_kernel(const int2* __restrict__ edges, int* __restrict__ offs_a,
                            int* __restrict__ cntN, int* __restrict__ cntF,
                            int* __restrict__ deg_ovf, int E, int V) {
    int i = blockIdx.x * blockDim.x + threadIdx.x;
    if (i <= E) {
        if (i < E) {
            int lo = (i == 0) ? 0 : edges[i - 1].x + 1;
            int hi = edges[i].x;
            for (int a = lo; a <= hi; a++) offs_a[a] = i;
        } else {
            for (int a = edges[E - 1].x + 1; a <= V; a++) offs_a[a] = E;
        }
    }
    if (i < V) deg_ovf[i] = 0;
    if (i <= RNG) cntF[i] = 0;   // vertices with no far-owner block
    if (i == 0) cntN[0] = 0;     // vertex 0 has no near-owner block
}

// build: heavy blocks (< NBb) do the b-side transpose via LDS-rank atomics into
// column-major near/far ELL; copy blocks (>= NBb) do faces->float (vectorized)
// and v->float4 repack on the ~165 CUs the heavy blocks leave idle.
// doOvf=0 (duplicate run): skip out-of-band atomics -> idempotent.
__global__ __launch_bounds__(TBS) void build_kernel(
        const int2* __restrict__ edges, const int* __restrict__ offs_a,
        int* __restrict__ cntN, int* __restrict__ cntF, int* __restrict__ deg_ovf,
        int* __restrict__ adjN, int* __restrict__ adjF, int* __restrict__ adj_ovf,
        const int* __restrict__ faces, float* __restrict__ out_f,
        const float* __restrict__ v, float4* __restrict__ v4,
        int E, int V, int F3, int NBb, int doOvf) {
    if ((int)blockIdx.x >= NBb) {
        int t = (blockIdx.x - NBb) * TBS + threadIdx.x;
        int T = (gridDim.x - NBb) * TBS;
        if ((((uintptr_t)out_f | (uintptr_t)faces) & 15) == 0) {
            int n4 = F3 >> 2;
            const int4* f4 = (const int4*)faces;
            float4* o4 = (float4*)out_f;
            for (int j = t; j < n4; j += T) {
                int4 a = f4[j];
                o4[j] = make_float4((float)a.x, (float)a.y, (float)a.z, (float)a.w);
            }
            for (int j = (n4 << 2) + t; j < F3; j += T) out_f[j] = (float)faces[j];
        } else {
            for (int j = t; j < F3; j += T) out_f[j] = (float)faces[j];
        }
        if (((uintptr_t)v & 15) == 0) {
            const float4* vv = (const float4*)v;
            int n4v = V >> 2;
            for (int q = t; q < n4v; q += T) {   // 3x float4 in -> 4x float4 out
                float4 a = vv[3 * q], b = vv[3 * q + 1], c = vv[3 * q + 2];
                v4[4 * q + 0] = make_float4(a.x, a.y, a.z, 0.f);
                v4[4 * q + 1] = make_float4(a.w, b.x, b.y, 0.f);
                v4[4 * q + 2] = make_float4(b.z, b.w, c.x, 0.f);
                v4[4 * q + 3] = make_float4(c.y, c.z, c.w, 0.f);
            }
            for (int u = (n4v << 2) + t; u < V; u += T)
                v4[u] = make_float4(v[3 * u], v[3 * u + 1], v[3 * u + 2], 0.f);
        } else {
            for (int u = t; u < V; u += T)
                v4[u] = make_float4(v[3 * u], v[3 * u + 1], v[3 * u + 2], 0.f);
        }
        return;
    }
    __shared__ int cnt[RW];
    const int v0   = blockIdx.x << RNG_LOG;
    const int vEnd = min(v0 + RNG, V);
    for (int i = threadIdx.x; i < RW; i += TBS) cnt[i] = 0;
    const int eBeg = offs_a[v0];
    const int eEnd = offs_a[vEnd];
    __syncthreads();
    for (int i = eBeg + threadIdx.x; i < eEnd; i += TBS) {
        int2 e = edges[i];
        int rel = e.y - (v0 + 1);            // b > a >= v0 -> rel >= 0
        if (rel < RW) {
            int r = atomicAdd(&cnt[rel], 1); // LDS rank = final ELL slot
            if (rel < RNG) { if (r < K_ELL) adjN[(size_t)r * V + e.y] = e.x; }
            else           { if (r < K_ELL) adjF[(size_t)r * V + e.y] = e.x; }
        } else if (doOvf) {                   // out-of-band fallback (rare; always correct)
            int r = atomicAdd(&deg_ovf[e.y], 1);
            if (r < K_OVF) adj_ovf[(size_t)r * V + e.y] = e.x;
        }
    }
    __syncthreads();
    for (int i = threadIdx.x; i < RW; i += TBS) {
        int u = v0 + 1 + i;
        if (u < V) {
            if (i < RNG) cntN[u] = cnt[i];   // unique near owner
            else         cntF[u] = cnt[i];   // unique far owner (BAND == RNG)
        }
    }
}

// gather: lambd==1 -> y = nbr_sum/deg (deg==0 -> 0, matches ref).
// XCD-swizzled; 3 latency levels; masked slots clamp to broadcast index 0.
template <bool PAD>
__global__ void gather_kernel(const float4* __restrict__ x4, const int2* __restrict__ edges,
                              const int* __restrict__ offs_a,
                              const int* __restrict__ cntN, const int* __restrict__ cntF,
                              const int* __restrict__ deg_ovf,
                              const int* __restrict__ adjN, const int* __restrict__ adjF,
                              const int* __restrict__ adj_ovf,
                              float* __restrict__ y, int V, int E) {
    int u = xcd_swz((int)blockIdx.x, (int)gridDim.x) * BS + (int)threadIdx.x;
    if (u >= V) return;
    int aBeg = offs_a[u], aEnd = offs_a[u + 1];
    int cN = cntN[u], cF = cntF[u], dO = deg_ovf[u];
    int da = aEnd - aBeg;
    int kN = cN > K_ELL ? K_ELL : cN;
    int kF = cF > K_ELL ? K_ELL : cF;
    // ---- level 2: all neighbor-index loads issue together ----
    int gA[UA], gN[UN], gF[UF];
    #pragma unroll
    for (int j = 0; j < UA; ++j) gA[j] = edges[min(aBeg + j, E - 1)].y;  // in-bounds
    #pragma unroll
    for (int k = 0; k < UN; ++k) gN[k] = adjN[(size_t)k * V + u];        // coalesced plane reads
    #pragma unroll
    for (int k = 0; k < UF; ++k) gF[k] = adjF[(size_t)k * V + u];
    // ---- level 3: value loads, mask-multiplied ----
    float s0 = 0.f, s1 = 0.f, s2 = 0.f;
    #pragma unroll
    for (int j = 0; j < UA; ++j) {
        float m = (j < da) ? 1.f : 0.f;
        float4 p = x4[(j < da) ? gA[j] : 0];           // masked -> broadcast line
        s0 += m * p.x; s1 += m * p.y; s2 += m * p.z;
    }
    for (int j = UA; j < da; ++j) {                    // rare high-valence tail
        float4 p = x4[edges[aBeg + j].y];
        s0 += p.x; s1 += p.y; s2 += p.z;
    }
    #pragma unroll
    for (int k = 0; k < UN; ++k) {
        float m = (k < kN) ? 1.f : 0.f;
        float4 p = x4[(k < kN) ? gN[k] : 0];
        s0 += m * p.x; s1 += m * p.y; s2 += m * p.z;
    }
    for (int k = UN; k < kN; ++k) {
        float4 p = x4[adjN[(size_t)k * V + u]];
        s0 += p.x; s1 += p.y; s2 += p.z;
    }
    #pragma unroll
    for (int k = 0; k < UF; ++k) {
        float m = (k < kF) ? 1.f : 0.f;
        float4 p = x4[(k < kF) ? gF[k] : 0];
        s0 += m * p.x; s1 += m * p.y; s2 += m * p.z;
    }
    for (int k = UF; k < kF; ++k) {
        float4 p = x4[adjF[(size_t)k * V + u]];
        s0 += p.x; s1 += p.y; s2 += p.z;
    }
    int kO = dO > K_OVF ? K_OVF : dO;
    for (int k = 0; k < kO; ++k) {                     // expected empty
        float4 p = x4[adj_ovf[(size_t)k * V + u]];
        s0 += p.x; s1 += p.y; s2 += p.z;
    }
    int d = da + cN + cF + dO;
    float inv = 1.0f / fmaxf((float)d, 1.0f);
    if (PAD) {
        ((float4*)y)[u] = make_float4(s0 * inv, s1 * inv, s2 * inv, 0.f);
    } else {
        y[3 * u + 0] = s0 * inv;
        y[3 * u + 1] = s1 * inv;
        y[3 * u + 2] = s2 * inv;
    }
}

extern "C" void kernel_launch(void* const* d_in, const int* in_sizes, int n_in,
                              void* d_out, int out_size, void* d_ws, size_t ws_size,
                              hipStream_t stream) {
    const float* v     = (const float*)d_in[0];  // [V,3]
    const int2*  edges = (const int2*)d_in[1];   // [E,2], rows lex-sorted, a<b
    const int*   faces = (const int*)d_in[2];    // [F,3]

    const int V3 = in_sizes[0];
    const int V  = V3 / 3;
    const int E  = in_sizes[1] / 2;
    const int F3 = in_sizes[2];

    float* out_v = (float*)d_out;
    float* out_f = (float*)d_out + V3;

    // ws layout (16B-aligned float4 arrays first): v4[V] | x1[V] | adjN[K_ELL*V] |
    //   adjF[K_ELL*V] | adj_ovf[K_OVF*V] | offs_a[V+1] | cntN[V+1] | cntF[V+1] | deg_ovf[V]
    float4* v4      = (float4*)d_ws;
    float4* x1      = v4 + V;
    int*    adjN    = (int*)(x1 + V);
    int*    adjF    = adjN + (size_t)K_ELL * V;
    int*    adj_ovf = adjF + (size_t)K_ELL * V;
    int*    offs_a  = adj_ovf + (size_t)K_OVF * V;
    int*    cntN    = offs_a + (V + 1);
    int*    cntF    = cntN + (V + 1);
    int*    deg_ovf = cntF + (V + 1);

    const int NBb = (V + RNG - 1) / RNG;          // heavy build blocks (~91)
    const int copyElems = F3 > V ? F3 : V;
    const int NBc = (copyElems + TBS - 1) / TBS;  // copy blocks (~1086)
    const int gP  = (E + 1 + BS - 1) / BS;        // prep covers edges (+V zeroing folded)
    const int gV  = (V + BS - 1) / BS;

    prep_kernel<<<gP, BS, 0, stream>>>(edges, offs_a, cntN, cntF, deg_ovf, E, V);

    build_kernel<<<NBb + NBc, TBS, 0, stream>>>(edges, offs_a, cntN, cntF, deg_ovf,
                                                adjN, adjF, adj_ovf, faces, out_f,
                                                v, v4, E, V, F3, NBb, 1);
    // MEASUREMENT: duplicate build with doOvf=0 (idempotent re-scatter; skips
    // ovf atomics so deg_ovf/adj_ovf keep run-1 state). dur delta = build + B.
    build_kernel<<<NBb + NBc, TBS, 0, stream>>>(edges, offs_a, cntN, cntF, deg_ovf,
                                                adjN, adjF, adj_ovf, faces, out_f,
                                                v, v4, E, V, F3, NBb, 0);

    gather_kernel<true ><<<gV, BS, 0, stream>>>(v4, edges, offs_a, cntN, cntF, deg_ovf,
                                                adjN, adjF, adj_ovf, (float*)x1, V, E);
    gather_kernel<false><<<gV, BS, 0, stream>>>(x1, edges, offs_a, cntN, cntF, deg_ovf,
                                                adjN, adjF, adj_ovf, out_v, V, E);
}

// Round 11
// 88.626 us; speedup vs baseline: 1.0737x; 1.0479x over previous
//
#include <hip/hip_runtime.h>
#include <stdint.h>

#define K_ELL 32      // ELL planes per near/far array (column-major; untouched planes = 0 traffic)
#define K_OVF 16      // overflow planes (out-of-band fallback, expected ~empty)
#define TBS   1024    // build block size
#define RNG_LOG 11
#define RNG   2048    // build block a-range
#define BAND  2048    // in-band limit on (b - v0 - 1); == RNG so each vertex has unique far owner
#define RW    (RNG + BAND)   // 4096 ints = 16 KB LDS
#define BS    256
#define UA    6       // unrolled a-side slots
#define UN    6       // unrolled near-ELL slots
#define UF    4       // unrolled far-ELL slots
#define NXCD  8

// bijective XCD-aware swizzle (m204): blocks with the same hw id % 8 (same XCD)
// get a CONTIGUOUS range of logical block ids -> each XCD owns one vertex band.
__device__ __forceinline__ int xcd_swz(int bid, int nwg) {
    int q = nwg >> 3, r = nwg & 7;
    int x = bid & 7, idx = bid >> 3;
    return (x < r ? x * (q + 1) : r * (q + 1) + (x - r) * q) + idx;
}

// wave-parallel lower_bound: first idx with edges[idx].x >= t. 64 lanes probe
// 64 split points per round -> range shrinks 64x/round (3 dependent loads for
// E~560K vs ~20 for serial bisection — R7's regression). All lanes return lb.
__device__ __forceinline__ int wave_lb(const int2* __restrict__ edges, int E,
                                       int t, int lane) {
    int lo = 0, hi = E;                       // invariant: lb in [lo, hi]
    while (hi > lo) {
        int span = hi - lo;
        if (span <= 64) {                     // exact tail: one probe per lane
            int p = lo + lane;
            int val = (p < hi) ? edges[p].x : 0x7fffffff;
            unsigned long long b = __ballot(val < t);
            return lo + __popcll(b);
        }
        long long sp = span;
        int p = lo + (int)(sp * lane / 64);   // p_l, monotone in l
        int val = edges[p].x;
        unsigned long long b = __ballot(val < t);
        int k = __popcll(b);                  // lanes 0..k-1 have val < t
        if (k == 0) return lo;                // edges[lo].x >= t -> lb == lo
        int nlo = lo + (int)(sp * (k - 1) / 64) + 1;     // p_{k-1}+1
        int nhi = (k == 64) ? hi : lo + (int)(sp * k / 64);  // p_k
        lo = nlo; hi = nhi;
    }
    return lo;
}

// build: heavy blocks (< NBb) self-locate their edge range via wave-parallel
// lower_bound (waves 0/1), then do the b-side transpose via LDS-rank atomics
// into column-major near/far ELL. Copy blocks (>= NBb) do faces->float
// (vectorized), v->float4 repack, offs_a construction (gather-only consumer),
// and cntF[0..RNG]/cntN[0] zeroing — all regions disjoint from heavy-block
// writes (window w dumps cntN[v0+1..v0+2048], cntF[v0+2049..v0+4097]).
// deg_ovf is pre-zeroed by hipMemsetAsync.
__global__ __launch_bounds__(TBS) void build_kernel(
        const int2* __restrict__ edges, int* __restrict__ offs_a,
        int* __restrict__ cntN, int* __restrict__ cntF, int* __restrict__ deg_ovf,
        int* __restrict__ adjN, int* __restrict__ adjF, int* __restrict__ adj_ovf,
        const int* __restrict__ faces, float* __restrict__ out_f,
        const float* __restrict__ v, float4* __restrict__ v4,
        int E, int V, int F3, int NBb) {
    if ((int)blockIdx.x >= NBb) {
        int t = (blockIdx.x - NBb) * TBS + threadIdx.x;
        int T = (gridDim.x - NBb) * TBS;
        // ---- faces -> float (vectorized) ----
        if ((((uintptr_t)out_f | (uintptr_t)faces) & 15) == 0) {
            int n4 = F3 >> 2;
            const int4* f4 = (const int4*)faces;
            float4* o4 = (float4*)out_f;
            for (int j = t; j < n4; j += T) {
                int4 a = f4[j];
                o4[j] = make_float4((float)a.x, (float)a.y, (float)a.z, (float)a.w);
            }
            for (int j = (n4 << 2) + t; j < F3; j += T) out_f[j] = (float)faces[j];
        } else {
            for (int j = t; j < F3; j += T) out_f[j] = (float)faces[j];
        }
        // ---- v[V,3] -> v4[V] float4 repack (vectorized) ----
        if (((uintptr_t)v & 15) == 0) {
            const float4* vv = (const float4*)v;
            int n4v = V >> 2;
            for (int q = t; q < n4v; q += T) {   // 3x float4 in -> 4x float4 out
                float4 a = vv[3 * q], b = vv[3 * q + 1], c = vv[3 * q + 2];
                v4[4 * q + 0] = make_float4(a.x, a.y, a.z, 0.f);
                v4[4 * q + 1] = make_float4(a.w, b.x, b.y, 0.f);
                v4[4 * q + 2] = make_float4(b.z, b.w, c.x, 0.f);
                v4[4 * q + 3] = make_float4(c.y, c.z, c.w, 0.f);
            }
            for (int u = (n4v << 2) + t; u < V; u += T)
                v4[u] = make_float4(v[3 * u], v[3 * u + 1], v[3 * u + 2], 0.f);
        } else {
            for (int u = t; u < V; u += T)
                v4[u] = make_float4(v[3 * u], v[3 * u + 1], v[3 * u + 2], 0.f);
        }
        // ---- offs_a[u] = first edge with .x >= u (read only by gathers) ----
        for (int i = t; i <= E; i += T) {
            if (i < E) {
                int lo = (i == 0) ? 0 : edges[i - 1].x + 1;
                int hi = edges[i].x;
                for (int a = lo; a <= hi; ++a) offs_a[a] = i;
            } else {
                int lo = (E > 0) ? edges[E - 1].x + 1 : 0;
                for (int a = lo; a <= V; ++a) offs_a[a] = E;
            }
        }
        // ---- zero counter slots no heavy block dumps (disjoint regions) ----
        for (int i = t; i <= RNG && i < V; i += T) cntF[i] = 0;
        if (t == 0) cntN[0] = 0;
        return;
    }
    __shared__ int cnt[RW];
    __shared__ int s_e[2];
    const int v0   = blockIdx.x << RNG_LOG;
    const int vEnd = min(v0 + RNG, V);
    const int wave = (int)threadIdx.x >> 6;
    const int lane = (int)threadIdx.x & 63;
    for (int i = threadIdx.x; i < RW; i += TBS) cnt[i] = 0;
    if (wave == 0) {                 // wave-parallel search, 2 waves concurrent
        int r = wave_lb(edges, E, v0, lane);
        if (lane == 0) s_e[0] = r;
    } else if (wave == 1) {
        int r = wave_lb(edges, E, vEnd, lane);
        if (lane == 0) s_e[1] = r;
    }
    __syncthreads();
    const int eBeg = s_e[0];
    const int eEnd = s_e[1];
    for (int i = eBeg + (int)threadIdx.x; i < eEnd; i += TBS) {
        int2 e = edges[i];
        int rel = e.y - (v0 + 1);            // b > a >= v0 -> rel >= 0
        if (rel < RW) {
            int r = atomicAdd(&cnt[rel], 1); // LDS rank = final ELL slot
            if (rel < RNG) { if (r < K_ELL) adjN[(size_t)r * V + e.y] = e.x; }
            else           { if (r < K_ELL) adjF[(size_t)r * V + e.y] = e.x; }
        } else {                              // out-of-band fallback (rare; always correct)
            int r = atomicAdd(&deg_ovf[e.y], 1);
            if (r < K_OVF) adj_ovf[(size_t)r * V + e.y] = e.x;
        }
    }
    __syncthreads();
    for (int i = threadIdx.x; i < RW; i += TBS) {
        int u = v0 + 1 + i;
        if (u < V) {
            if (i < RNG) cntN[u] = cnt[i];   // unique near owner
            else         cntF[u] = cnt[i];   // unique far owner (BAND == RNG)
        }
    }
}

// gather (R8 verbatim, proven best): lambd==1 -> y = nbr_sum/deg.
// XCD-swizzled; 3 latency levels; masked slots clamp to broadcast index 0.
template <bool PAD>
__global__ void gather_kernel(const float4* __restrict__ x4, const int2* __restrict__ edges,
                              const int* __restrict__ offs_a,
                              const int* __restrict__ cntN, const int* __restrict__ cntF,
                              const int* __restrict__ deg_ovf,
                              const int* __restrict__ adjN, const int* __restrict__ adjF,
                              const int* __restrict__ adj_ovf,
                              float* __restrict__ y, int V, int E) {
    int u = xcd_swz((int)blockIdx.x, (int)gridDim.x) * BS + (int)threadIdx.x;
    if (u >= V) return;
    int aBeg = offs_a[u], aEnd = offs_a[u + 1];
    int cN = cntN[u], cF = cntF[u], dO = deg_ovf[u];
    int da = aEnd - aBeg;
    int kN = cN > K_ELL ? K_ELL : cN;
    int kF = cF > K_ELL ? K_ELL : cF;
    // ---- level 2: all neighbor-index loads issue together ----
    int gA[UA], gN[UN], gF[UF];
    #pragma unroll
    for (int j = 0; j < UA; ++j) gA[j] = edges[min(aBeg + j, E - 1)].y;  // in-bounds
    #pragma unroll
    for (int k = 0; k < UN; ++k) gN[k] = adjN[(size_t)k * V + u];        // coalesced plane reads
    #pragma unroll
    for (int k = 0; k < UF; ++k) gF[k] = adjF[(size_t)k * V + u];
    // ---- level 3: value loads, mask-multiplied ----
    float s0 = 0.f, s1 = 0.f, s2 = 0.f;
    #pragma unroll
    for (int j = 0; j < UA; ++j) {
        float m = (j < da) ? 1.f : 0.f;
        float4 p = x4[(j < da) ? gA[j] : 0];           // masked -> broadcast line
        s0 += m * p.x; s1 += m * p.y; s2 += m * p.z;
    }
    for (int j = UA; j < da; ++j) {                    // rare high-valence tail
        float4 p = x4[edges[aBeg + j].y];
        s0 += p.x; s1 += p.y; s2 += p.z;
    }
    #pragma unroll
    for (int k = 0; k < UN; ++k) {
        float m = (k < kN) ? 1.f : 0.f;
        float4 p = x4[(k < kN) ? gN[k] : 0];
        s0 += m * p.x; s1 += m * p.y; s2 += m * p.z;
    }
    for (int k = UN; k < kN; ++k) {
        float4 p = x4[adjN[(size_t)k * V + u]];
        s0 += p.x; s1 += p.y; s2 += p.z;
    }
    #pragma unroll
    for (int k = 0; k < UF; ++k) {
        float m = (k < kF) ? 1.f : 0.f;
        float4 p = x4[(k < kF) ? gF[k] : 0];
        s0 += m * p.x; s1 += m * p.y; s2 += m * p.z;
    }
    for (int k = UF; k < kF; ++k) {
        float4 p = x4[adjF[(size_t)k * V + u]];
        s0 += p.x; s1 += p.y; s2 += p.z;
    }
    int kO = dO > K_OVF ? K_OVF : dO;
    for (int k = 0; k < kO; ++k) {                     // expected empty
        float4 p = x4[adj_ovf[(size_t)k * V + u]];
        s0 += p.x; s1 += p.y; s2 += p.z;
    }
    int d = da + cN + cF + dO;
    float inv = 1.0f / fmaxf((float)d, 1.0f);
    if (PAD) {
        ((float4*)y)[u] = make_float4(s0 * inv, s1 * inv, s2 * inv, 0.f);
    } else {
        y[3 * u + 0] = s0 * inv;
        y[3 * u + 1] = s1 * inv;
        y[3 * u + 2] = s2 * inv;
    }
}

extern "C" void kernel_launch(void* const* d_in, const int* in_sizes, int n_in,
                              void* d_out, int out_size, void* d_ws, size_t ws_size,
                              hipStream_t stream) {
    const float* v     = (const float*)d_in[0];  // [V,3]
    const int2*  edges = (const int2*)d_in[1];   // [E,2], rows lex-sorted, a<b
    const int*   faces = (const int*)d_in[2];    // [F,3]

    const int V3 = in_sizes[0];
    const int V  = V3 / 3;
    const int E  = in_sizes[1] / 2;
    const int F3 = in_sizes[2];

    float* out_v = (float*)d_out;
    float* out_f = (float*)d_out + V3;

    // ws layout (16B-aligned float4 arrays first): v4[V] | x1[V] | adjN[K_ELL*V] |
    //   adjF[K_ELL*V] | adj_ovf[K_OVF*V] | offs_a[V+1] | cntN[V+1] | cntF[V+1] | deg_ovf[V]
    float4* v4      = (float4*)d_ws;
    float4* x1      = v4 + V;
    int*    adjN    = (int*)(x1 + V);
    int*    adjF    = adjN + (size_t)K_ELL * V;
    int*    adj_ovf = adjF + (size_t)K_ELL * V;
    int*    offs_a  = adj_ovf + (size_t)K_OVF * V;
    int*    cntN    = offs_a + (V + 1);
    int*    cntF    = cntN + (V + 1);
    int*    deg_ovf = cntF + (V + 1);

    const int NBb = (V + RNG - 1) / RNG;          // heavy build blocks (~91)
    const int copyElems = F3 > V ? F3 : V;
    const int NBc = (copyElems + TBS - 1) / TBS;  // copy blocks (~1086)
    const int gV  = (V + BS - 1) / BS;

    // node 1: zero deg_ovf (build's out-of-band atomics need 0) — 0.75 MB
    (void)hipMemsetAsync(deg_ovf, 0, (size_t)V * sizeof(int), stream);

    // node 2: build (heavy windows self-locate via wave-parallel search;
    // copy blocks absorb offs_a + counter-slot zeroing) — prep kernel gone
    build_kernel<<<NBb + NBc, TBS, 0, stream>>>(edges, offs_a, cntN, cntF, deg_ovf,
                                                adjN, adjF, adj_ovf, faces, out_f,
                                                v, v4, E, V, F3, NBb);

    // nodes 3+4: two smoothing rounds
    gather_kernel<true ><<<gV, BS, 0, stream>>>(v4, edges, offs_a, cntN, cntF, deg_ovf,
                                                adjN, adjF, adj_ovf, (float*)x1, V, E);
    gather_kernel<false><<<gV, BS, 0, stream>>>(x1, edges, offs_a, cntN, cntF, deg_ovf,
                                                adjN, adjF, adj_ovf, out_v, V, E);
}

// Round 12
// 85.541 us; speedup vs baseline: 1.1124x; 1.0361x over previous
//
#include <hip/hip_runtime.h>
#include <stdint.h>

// ============================================================================
// R8 restore (session best: 85.54 us, absmax 0.0).
// Chain decomposition (R9/R10 duplicate-dispatch measurements):
//   poison fill 43.4 | fixed overhead ~30 | prep ~2.5 | build ~5 | g1+g2 ~5-7
// All structural alternatives measured worse: coop mega-kernel (R2, +gridsync
// stalls), LDS-staged gather (R5, +17.5), global-atomic build (R6, +10.5),
// prep folded into build (R7 +7.9 serial, R11 +3.1 parallel).
// ============================================================================

#define K_ELL 32      // ELL planes per near/far array (column-major; untouched planes = 0 traffic)
#define K_OVF 16      // overflow planes (out-of-band fallback, expected ~empty)
#define TBS   1024    // build block size
#define RNG_LOG 11
#define RNG   2048    // build block a-range
#define BAND  2048    // in-band limit on (b - v0 - 1); == RNG so each vertex has unique far owner
#define RW    (RNG + BAND)   // 4096 ints = 16 KB LDS
#define BS    256
#define UA    6       // unrolled a-side slots
#define UN    6       // unrolled near-ELL slots
#define UF    4       // unrolled far-ELL slots
#define NXCD  8

// bijective XCD-aware swizzle (m204): blocks with the same hw id % 8 (same XCD)
// get a CONTIGUOUS range of logical block ids -> each XCD owns one vertex band.
__device__ __forceinline__ int xcd_swz(int bid, int nwg) {
    int q = nwg >> 3, r = nwg & 7;
    int x = bid & 7, idx = bid >> 3;
    return (x < r ? x * (q + 1) : r * (q + 1) + (x - r) * q) + idx;
}

// prep (light): offs_a[u] = first edge index with edges[.].x >= u (edges[:,0]
// sorted asc, a<b); zero the counters build's LDS dumps don't cover.
__global__ void prep_kernel(const int2* __restrict__ edges, int* __restrict__ offs_a,
                            int* __restrict__ cntN, int* __restrict__ cntF,
                            int* __restrict__ deg_ovf, int E, int V) {
    int i = blockIdx.x * blockDim.x + threadIdx.x;
    if (i <= E) {
        if (i < E) {
            int lo = (i == 0) ? 0 : edges[i - 1].x + 1;
            int hi = edges[i].x;
            for (int a = lo; a <= hi; a++) offs_a[a] = i;
        } else {
            for (int a = edges[E - 1].x + 1; a <= V; a++) offs_a[a] = E;
        }
    }
    if (i < V) deg_ovf[i] = 0;
    if (i <= RNG) cntF[i] = 0;   // vertices with no far-owner block
    if (i == 0) cntN[0] = 0;     // vertex 0 has no near-owner block
}

// build: heavy blocks (< NBb) do the b-side transpose via LDS-rank atomics into
// column-major near/far ELL; copy blocks (>= NBb) do faces->float (vectorized)
// and v->float4 repack on the ~165 CUs the heavy blocks leave idle.
__global__ __launch_bounds__(TBS) void build_kernel(
        const int2* __restrict__ edges, const int* __restrict__ offs_a,
        int* __restrict__ cntN, int* __restrict__ cntF, int* __restrict__ deg_ovf,
        int* __restrict__ adjN, int* __restrict__ adjF, int* __restrict__ adj_ovf,
        const int* __restrict__ faces, float* __restrict__ out_f,
        const float* __restrict__ v, float4* __restrict__ v4,
        int E, int V, int F3, int NBb) {
    if ((int)blockIdx.x >= NBb) {
        int t = (blockIdx.x - NBb) * TBS + threadIdx.x;
        int T = (gridDim.x - NBb) * TBS;
        if ((((uintptr_t)out_f | (uintptr_t)faces) & 15) == 0) {
            int n4 = F3 >> 2;
            const int4* f4 = (const int4*)faces;
            float4* o4 = (float4*)out_f;
            for (int j = t; j < n4; j += T) {
                int4 a = f4[j];
                o4[j] = make_float4((float)a.x, (float)a.y, (float)a.z, (float)a.w);
            }
            for (int j = (n4 << 2) + t; j < F3; j += T) out_f[j] = (float)faces[j];
        } else {
            for (int j = t; j < F3; j += T) out_f[j] = (float)faces[j];
        }
        if (((uintptr_t)v & 15) == 0) {
            const float4* vv = (const float4*)v;
            int n4v = V >> 2;
            for (int q = t; q < n4v; q += T) {   // 3x float4 in -> 4x float4 out
                float4 a = vv[3 * q], b = vv[3 * q + 1], c = vv[3 * q + 2];
                v4[4 * q + 0] = make_float4(a.x, a.y, a.z, 0.f);
                v4[4 * q + 1] = make_float4(a.w, b.x, b.y, 0.f);
                v4[4 * q + 2] = make_float4(b.z, b.w, c.x, 0.f);
                v4[4 * q + 3] = make_float4(c.y, c.z, c.w, 0.f);
            }
            for (int u = (n4v << 2) + t; u < V; u += T)
                v4[u] = make_float4(v[3 * u], v[3 * u + 1], v[3 * u + 2], 0.f);
        } else {
            for (int u = t; u < V; u += T)
                v4[u] = make_float4(v[3 * u], v[3 * u + 1], v[3 * u + 2], 0.f);
        }
        return;
    }
    __shared__ int cnt[RW];
    const int v0   = blockIdx.x << RNG_LOG;
    const int vEnd = min(v0 + RNG, V);
    for (int i = threadIdx.x; i < RW; i += TBS) cnt[i] = 0;
    const int eBeg = offs_a[v0];
    const int eEnd = offs_a[vEnd];
    __syncthreads();
    for (int i = eBeg + threadIdx.x; i < eEnd; i += TBS) {
        int2 e = edges[i];
        int rel = e.y - (v0 + 1);            // b > a >= v0 -> rel >= 0
        if (rel < RW) {
            int r = atomicAdd(&cnt[rel], 1); // LDS rank = final ELL slot
            if (rel < RNG) { if (r < K_ELL) adjN[(size_t)r * V + e.y] = e.x; }
            else           { if (r < K_ELL) adjF[(size_t)r * V + e.y] = e.x; }
        } else {                              // out-of-band fallback (rare; always correct)
            int r = atomicAdd(&deg_ovf[e.y], 1);
            if (r < K_OVF) adj_ovf[(size_t)r * V + e.y] = e.x;
        }
    }
    __syncthreads();
    for (int i = threadIdx.x; i < RW; i += TBS) {
        int u = v0 + 1 + i;
        if (u < V) {
            if (i < RNG) cntN[u] = cnt[i];   // unique near owner
            else         cntF[u] = cnt[i];   // unique far owner (BAND == RNG)
        }
    }
}

// gather: lambd==1 -> y = nbr_sum/deg (deg==0 -> 0, matches ref).
// XCD-swizzled: each XCD owns a contiguous vertex band -> x4/x1 band stays in
// that XCD's L2 across both rounds. 3 latency levels; ALL masked slots clamp
// to index 0 (wave-broadcast line, ~free). Masked lanes add m*p = +0.0 ->
// bit-exact, accumulation order preserved.
template <bool PAD>
__global__ void gather_kernel(const float4* __restrict__ x4, const int2* __restrict__ edges,
                              const int* __restrict__ offs_a,
                              const int* __restrict__ cntN, const int* __restrict__ cntF,
                              const int* __restrict__ deg_ovf,
                              const int* __restrict__ adjN, const int* __restrict__ adjF,
                              const int* __restrict__ adj_ovf,
                              float* __restrict__ y, int V, int E) {
    int u = xcd_swz((int)blockIdx.x, (int)gridDim.x) * BS + (int)threadIdx.x;
    if (u >= V) return;
    int aBeg = offs_a[u], aEnd = offs_a[u + 1];
    int cN = cntN[u], cF = cntF[u], dO = deg_ovf[u];
    int da = aEnd - aBeg;
    int kN = cN > K_ELL ? K_ELL : cN;
    int kF = cF > K_ELL ? K_ELL : cF;
    // ---- level 2: all neighbor-index loads issue together ----
    int gA[UA], gN[UN], gF[UF];
    #pragma unroll
    for (int j = 0; j < UA; ++j) gA[j] = edges[min(aBeg + j, E - 1)].y;  // in-bounds
    #pragma unroll
    for (int k = 0; k < UN; ++k) gN[k] = adjN[(size_t)k * V + u];        // coalesced plane reads
    #pragma unroll
    for (int k = 0; k < UF; ++k) gF[k] = adjF[(size_t)k * V + u];
    // ---- level 3: value loads, mask-multiplied ----
    float s0 = 0.f, s1 = 0.f, s2 = 0.f;
    #pragma unroll
    for (int j = 0; j < UA; ++j) {
        float m = (j < da) ? 1.f : 0.f;
        float4 p = x4[(j < da) ? gA[j] : 0];           // masked -> broadcast line
        s0 += m * p.x; s1 += m * p.y; s2 += m * p.z;
    }
    for (int j = UA; j < da; ++j) {                    // rare high-valence tail
        float4 p = x4[edges[aBeg + j].y];
        s0 += p.x; s1 += p.y; s2 += p.z;
    }
    #pragma unroll
    for (int k = 0; k < UN; ++k) {
        float m = (k < kN) ? 1.f : 0.f;
        float4 p = x4[(k < kN) ? gN[k] : 0];
        s0 += m * p.x; s1 += m * p.y; s2 += m * p.z;
    }
    for (int k = UN; k < kN; ++k) {
        float4 p = x4[adjN[(size_t)k * V + u]];
        s0 += p.x; s1 += p.y; s2 += p.z;
    }
    #pragma unroll
    for (int k = 0; k < UF; ++k) {
        float m = (k < kF) ? 1.f : 0.f;
        float4 p = x4[(k < kF) ? gF[k] : 0];
        s0 += m * p.x; s1 += m * p.y; s2 += m * p.z;
    }
    for (int k = UF; k < kF; ++k) {
        float4 p = x4[adjF[(size_t)k * V + u]];
        s0 += p.x; s1 += p.y; s2 += p.z;
    }
    int kO = dO > K_OVF ? K_OVF : dO;
    for (int k = 0; k < kO; ++k) {                     // expected empty
        float4 p = x4[adj_ovf[(size_t)k * V + u]];
        s0 += p.x; s1 += p.y; s2 += p.z;
    }
    int d = da + cN + cF + dO;
    float inv = 1.0f / fmaxf((float)d, 1.0f);
    if (PAD) {
        ((float4*)y)[u] = make_float4(s0 * inv, s1 * inv, s2 * inv, 0.f);
    } else {
        y[3 * u + 0] = s0 * inv;
        y[3 * u + 1] = s1 * inv;
        y[3 * u + 2] = s2 * inv;
    }
}

extern "C" void kernel_launch(void* const* d_in, const int* in_sizes, int n_in,
                              void* d_out, int out_size, void* d_ws, size_t ws_size,
                              hipStream_t stream) {
    const float* v     = (const float*)d_in[0];  // [V,3]
    const int2*  edges = (const int2*)d_in[1];   // [E,2], rows lex-sorted, a<b
    const int*   faces = (const int*)d_in[2];    // [F,3]

    const int V3 = in_sizes[0];
    const int V  = V3 / 3;
    const int E  = in_sizes[1] / 2;
    const int F3 = in_sizes[2];

    float* out_v = (float*)d_out;
    float* out_f = (float*)d_out + V3;

    // ws layout (16B-aligned float4 arrays first): v4[V] | x1[V] | adjN[K_ELL*V] |
    //   adjF[K_ELL*V] | adj_ovf[K_OVF*V] | offs_a[V+1] | cntN[V+1] | cntF[V+1] | deg_ovf[V]
    float4* v4      = (float4*)d_ws;
    float4* x1      = v4 + V;
    int*    adjN    = (int*)(x1 + V);
    int*    adjF    = adjN + (size_t)K_ELL * V;
    int*    adj_ovf = adjF + (size_t)K_ELL * V;
    int*    offs_a  = adj_ovf + (size_t)K_OVF * V;
    int*    cntN    = offs_a + (V + 1);
    int*    cntF    = cntN + (V + 1);
    int*    deg_ovf = cntF + (V + 1);

    const int NBb = (V + RNG - 1) / RNG;          // heavy build blocks (~91)
    const int copyElems = F3 > V ? F3 : V;
    const int NBc = (copyElems + TBS - 1) / TBS;  // copy blocks (~1086)
    const int gP  = (E + 1 + BS - 1) / BS;        // prep covers edges (+V zeroing folded)
    const int gV  = (V + BS - 1) / BS;

    prep_kernel<<<gP, BS, 0, stream>>>(edges, offs_a, cntN, cntF, deg_ovf, E, V);

    build_kernel<<<NBb + NBc, TBS, 0, stream>>>(edges, offs_a, cntN, cntF, deg_ovf,
                                                adjN, adjF, adj_ovf, faces, out_f,
                                                v, v4, E, V, F3, NBb);

    gather_kernel<true ><<<gV, BS, 0, stream>>>(v4, edges, offs_a, cntN, cntF, deg_ovf,
                                                adjN, adjF, adj_ovf, (float*)x1, V, E);
    gather_kernel<false><<<gV, BS, 0, stream>>>(x1, edges, offs_a, cntN, cntF, deg_ovf,
                                                adjN, adjF, adj_ovf, out_v, V, E);
}